// Round 9
// baseline (3035.312 us; speedup 1.0000x reference)
//
#include <hip/hip_runtime.h>

#define B_  64
#define Q_  512
#define C_  128
#define P_  2048
#define G_  256
#define BM  128            // q-tile per block
#define NT  512            // 8 waves; each owns P/8 = 256 persons
#define PW  (P_ / 8)
#define PAD 257            // acc row stride (floats): bank = (l+g)%32, 2-way = free

__device__ __forceinline__ float splus(float x) {
    // softplus(x) = max(x,0) + log1p(exp(-|x|))
    return fmaxf(x, 0.f) + __logf(1.f + __expf(-fabsf(x)));
}
__device__ __forceinline__ float u2f(unsigned int u) {
    union { unsigned int u; float f; } v; v.u = u; return v.f;
}
__device__ __forceinline__ unsigned int f2u(float f) {
    union { float f; unsigned int u; } v; v.f = f; return v.u;
}

// R8 post-mortem: GEMM scaffolding was the bottleneck, not the matmul
// (MfmaUtil never >8.4%; convert+barrier lockstep held 161.5us = 2.3x the
// 71us traffic floor). onehot is 0/1, density ~1/32 => xt is a sparse
// scatter: per person p, ballot its ~8 nonzero groups (wave-uniform),
// readlane the value, ds_add_f32 attw[p, qtile] into acc[128][257] f32.
//   - no MFMA, no bf16 convert, NO barriers in the p-loop (waves independent)
//   - grid (4,64)=256 blocks, 1/CU; lane l owns acc rows {l, l+64}
//   - ~32k ds_add wave-instr/block (~64k cyc) hides under HBM delivery
//   - 4-slot register prefetch keeps ~6KB/wave of loads in flight
// Traffic: attw 268MB once, onehot 134MB (4x logical, L3-absorbed: verified
// R2-R6), logits 16MB, out 33.5MB => ~71us floor at 6.3TB/s.
__global__ __launch_bounds__(NT, 1)
void fused_cost_kernel(const float* __restrict__ logits,
                       const float* __restrict__ attw,
                       const float* __restrict__ onehot,
                       const int* __restrict__ ids,
                       float* __restrict__ out)
{
    __shared__ float accf[BM * PAD];   // 131.6 KB
    __shared__ float spq[BM];
    __shared__ int idt[G_];
    __shared__ int sflags;

    const int tid = threadIdx.x;
    const int l   = tid & 63;
    const int w   = tid >> 6;          // 0..7
    const int q0  = blockIdx.x * BM;
    const int b   = blockIdx.y;

    for (int i = tid; i < BM * PAD; i += NT) accf[i] = 0.f;
    if (tid < BM) spq[tid] = 0.f;
    if (tid == 0) sflags = 0;
    __syncthreads();
    // ids int64-vs-int32 probe: odd words of first 128 entries all 0 iff int64
    if (tid < 128) { if (ids[2 * tid + 1] != 0) atomicOr(&sflags, 1); }
    __syncthreads();
    const bool ids32 = (sflags & 1) != 0;
    if (tid < G_) idt[tid] = ids32 ? ids[b * G_ + tid] : ids[2 * (b * G_ + tid)];

    // ---- logits pass: sp_a row means (loads overlap p-loop ramp) ----
    {
        const int q = tid >> 2, qt = tid & 3;   // 32 floats per thread
        const float4* src = (const float4*)(logits + ((size_t)b * Q_ + q0 + q) * C_ + 32 * qt);
        float s = 0.f;
        #pragma unroll
        for (int i = 0; i < 8; ++i) {
            float4 t = src[i];
            s += splus(t.x) + splus(t.y) + splus(t.z) + splus(t.w);
        }
        atomicAdd(&spq[q], s * (1.0f / C_));
    }

    // ---- sparse p-loop: wave w owns p in [w*PW, (w+1)*PW) ----
    const float* aRow = attw   + (size_t)b * P_ * Q_ + q0;  // + p*Q_ + l / l+64
    const float* oRow = onehot + (size_t)b * P_ * G_;        // + p*G_ + 4*l
    const int pb = w * PW;
    float sp0 = 0.f, sp1 = 0.f;
    float* const c0 = accf + l * PAD;          // row l
    float* const c1 = accf + (l + 64) * PAD;   // row l+64

#define LOADS(OH, A0, A1, ii) {                                        \
        const size_t pr = (size_t)(pb + (ii));                         \
        OH = *(const float4*)(oRow + pr * G_ + 4 * l);                 \
        A0 = aRow[pr * Q_ + l];                                        \
        A1 = aRow[pr * Q_ + l + 64]; }

#define SCAT(VAL, A0, A1, JOFF) {                                      \
        unsigned long long m = __ballot((VAL) != 0.f);                 \
        while (m) {                                                    \
            const int s = (int)__builtin_ctzll(m); m &= m - 1;         \
            const float v = u2f(__builtin_amdgcn_readlane(f2u(VAL), s)); \
            const int g = 4 * s + (JOFF);                              \
            atomicAdd(c0 + g, v * (A0));                               \
            atomicAdd(c1 + g, v * (A1)); } }

#define PROC(OH, A0, A1) {                                             \
        sp0 += splus(A0); sp1 += splus(A1);                            \
        SCAT(OH.x, A0, A1, 0)                                          \
        SCAT(OH.y, A0, A1, 1)                                          \
        SCAT(OH.z, A0, A1, 2)                                          \
        SCAT(OH.w, A0, A1, 3) }

    float4 oh0, oh1, oh2, oh3;
    float a00, a01, a10, a11, a20, a21, a30, a31;
    LOADS(oh0, a00, a01, 0)
    LOADS(oh1, a10, a11, 1)
    LOADS(oh2, a20, a21, 2)
    LOADS(oh3, a30, a31, 3)

    for (int i = 0; i < PW; i += 4) {
        PROC(oh0, a00, a01)
        { const int nx = (i + 4 < PW) ? i + 4 : PW - 1; LOADS(oh0, a00, a01, nx) }
        PROC(oh1, a10, a11)
        { const int nx = (i + 5 < PW) ? i + 5 : PW - 1; LOADS(oh1, a10, a11, nx) }
        PROC(oh2, a20, a21)
        { const int nx = (i + 6 < PW) ? i + 6 : PW - 1; LOADS(oh2, a20, a21, nx) }
        PROC(oh3, a30, a31)
        { const int nx = (i + 7 < PW) ? i + 7 : PW - 1; LOADS(oh3, a30, a31, nx) }
    }

    // merge sp_g partials (each wave covered all 128 q for its p-subset)
    atomicAdd(&spq[l],      sp0 * (1.0f / P_));
    atomicAdd(&spq[l + 64], sp1 * (1.0f / P_));

    __syncthreads();

    // ---- epilogue: cost = spq[q] - acc[q][g]/P - logits[b,q,ids[g]]/C ----
    const float* lbase = logits + ((size_t)b * Q_ + q0) * C_;
    float* obase = out + ((size_t)b * Q_ + q0) * G_;
    #pragma unroll 4
    for (int r = 0; r < (BM * G_) / NT; ++r) {   // 64 iters
        const int idx = r * NT + tid;
        const int q = idx >> 8;        // G_ = 256
        const int g = idx & 255;
        const float lg = lbase[q * C_ + idt[g]];
        obase[idx] = spq[q] - accf[q * PAD + g] * (1.0f / P_) - lg * (1.0f / C_);
    }
}

extern "C" void kernel_launch(void* const* d_in, const int* in_sizes, int n_in,
                              void* d_out, int out_size, void* d_ws, size_t ws_size,
                              hipStream_t stream) {
    const float* logits = (const float*)d_in[0];  // [B,Q,C] f32
    const float* attw   = (const float*)d_in[1];  // [B,P,Q] f32
    const float* onehot = (const float*)d_in[2];  // [B,P,G] f32 (0/1 sparse)
    const int*   ids    = (const int*)d_in[3];    // [B,G] int32/int64 (probed)
    float*       out    = (float*)d_out;          // [B,Q,G] f32

    dim3 grid(Q_ / BM, B_);
    hipLaunchKernelGGL(fused_cost_kernel, grid, dim3(NT), 0, stream,
                       logits, attw, onehot, ids, out);
}